// Round 2
// baseline (87.348 us; speedup 1.0000x reference)
//
#include <hip/hip_runtime.h>
#include <hip/hip_bf16.h>

// Problem constants
#define BATCH 32768
#define NIN   256
#define NOUT  256
// degrees 1..8 via MFMA; degree 0 (T_0 = 1) folded into per-column bias

typedef __attribute__((ext_vector_type(8))) short bf16x8;
typedef __attribute__((ext_vector_type(4))) float f32x4;
typedef __attribute__((ext_vector_type(2))) float f32x2;

static __device__ __forceinline__ unsigned short bf16_rne(float f) {
  unsigned u = __float_as_uint(f);
  u += 0x7fffu + ((u >> 16) & 1u);
  return (unsigned short)(u >> 16);
}

// fast tanh: t = sign(v) * (1 - z) / (1 + z), z = exp(-2|v|)
static __device__ __forceinline__ float fast_tanh(float v) {
  float a = fabsf(v);
  float z = __expf(-2.0f * a);
  float r = (1.0f - z) * __builtin_amdgcn_rcpf(1.0f + z);
  return copysignf(r, v);
}

// ---------------------------------------------------------------------------
// Prepack: Bp[((dm*8+ic)*16+tile)*512 + kg*128 + col*8 + j] =
//          bf16( c_basis[n][i][dm+1] * c_act[n][i] )
//   with i = ic*32 + kg*8 + j,  n = tile*16 + col.
// Linear output index == tid by construction. 8*256*256 = 524288 elements.
// ---------------------------------------------------------------------------
__global__ void cheby_prepack(const float* __restrict__ cb,
                              const float* __restrict__ ca,
                              unsigned short* __restrict__ Bp) {
  int tid = blockIdx.x * 256 + threadIdx.x;
  int j    = tid & 7;
  int col  = (tid >> 3) & 15;
  int kg   = (tid >> 7) & 3;
  int tile = (tid >> 9) & 15;
  int ic   = (tid >> 13) & 7;
  int dm   = tid >> 16;           // d-1, 0..7
  int i = ic * 32 + kg * 8 + j;
  int n = tile * 16 + col;
  float w = cb[n * (NIN * 9) + i * 9 + (dm + 1)] * ca[n * NIN + i];
  Bp[tid] = bf16_rne(w);
}

// bias[n] = sum_i c_basis[n][i][0] * c_act[n][i]   (T_0 == 1 term)
__global__ void cheby_bias(const float* __restrict__ cb,
                           const float* __restrict__ ca,
                           float* __restrict__ bias) {
  int n = blockIdx.x;
  int l = threadIdx.x;            // 64 threads = one wave
  float s = 0.0f;
  #pragma unroll
  for (int k = 0; k < 4; ++k) {
    int i = l + k * 64;
    s += cb[n * (NIN * 9) + i * 9] * ca[n * NIN + i];
  }
  #pragma unroll
  for (int off = 32; off; off >>= 1) s += __shfl_down(s, off);
  if (l == 0) bias[n] = s;
}

// ---------------------------------------------------------------------------
// Fused cheby + GEMM.
// Grid: 1024 blocks of 256 threads (4 waves).  Block tile: 32 rows x 256 cols.
// Wave tile: 16 rows x 128 cols (8 n-tiles) -> tanh/recurrence duplication 2x,
// A-frag amortized over 8 MFMAs, 4096 waves = 4 waves/SIMD occupancy.
// ---------------------------------------------------------------------------
__global__ __launch_bounds__(256, 4)
void cheby_mfma(const float* __restrict__ x,
                const unsigned short* __restrict__ Bp,
                const float* __restrict__ bias,
                float* __restrict__ out) {
  int w    = threadIdx.x >> 6;
  int lane = threadIdx.x & 63;
  int wr = w >> 1, wc = w & 1;
  int row16 = lane & 15;          // A row / B col / C-D col
  int kg    = lane >> 4;          // k-group 0..3

  int base_row = blockIdx.x * 32 + wr * 16;
  int tile0    = wc * 8;          // 8 column tiles of 16 -> 128 cols

  f32x4 acc[8];
  #pragma unroll
  for (int nt = 0; nt < 8; ++nt) acc[nt] = (f32x4)0.0f;

  // per-lane byte offset inside one 1KB B fragment
  const char* bp_lane = (const char*)Bp + (kg * 256 + row16 * 16);
  const float* xrow = x + ((size_t)(base_row + row16) * NIN);

  for (int ic = 0; ic < 8; ++ic) {
    // load this lane's 8 features, tanh once
    const float* xp = xrow + ic * 32 + kg * 8;
    f32x4 x0 = *(const f32x4*)xp;
    f32x4 x1 = *(const f32x4*)(xp + 4);
    f32x2 t2v[4], curv[4], prevv[4];
    #pragma unroll
    for (int p = 0; p < 4; ++p) {
      float va = (p < 2) ? x0[2 * p]     : x1[2 * p - 4];
      float vb = (p < 2) ? x0[2 * p + 1] : x1[2 * p - 3];
      float ta = fast_tanh(va);
      float tb = fast_tanh(vb);
      curv[p]  = (f32x2){ta, tb};          // T_1
      t2v[p]   = curv[p] + curv[p];
      prevv[p] = (f32x2){1.0f, 1.0f};      // T_0
    }
    #pragma unroll
    for (int d = 1; d <= 8; ++d) {
      // A fragment: bf16(T_d), paired converts -> v_cvt_pk_bf16_f32
      union { unsigned u[4]; bf16x8 v; } au;
      #pragma unroll
      for (int p = 0; p < 4; ++p) {
        __hip_bfloat162 h2 =
            __float22bfloat162_rn(make_float2(curv[p][0], curv[p][1]));
        union { __hip_bfloat162 h; unsigned u; } cv;
        cv.h = h2;
        au.u[p] = cv.u;
      }
      bf16x8 af = au.v;
      int fbase = ((d - 1) * 8 + ic) * 16 + tile0;
      #pragma unroll
      for (int nt = 0; nt < 8; ++nt) {
        bf16x8 bf = *(const bf16x8*)(bp_lane + (size_t)(fbase + nt) * 1024);
        acc[nt] = __builtin_amdgcn_mfma_f32_16x16x32_bf16(af, bf, acc[nt],
                                                          0, 0, 0);
      }
      if (d < 8) {   // T_{d+1} = 2t*T_d - T_{d-1}  (packed f32x2 fma)
        #pragma unroll
        for (int p = 0; p < 4; ++p) {
          f32x2 nx = __builtin_elementwise_fma(t2v[p], curv[p], -prevv[p]);
          prevv[p] = curv[p];
          curv[p]  = nx;
        }
      }
    }
  }

  // epilogue: C/D layout col = lane&15, row = (lane>>4)*4 + q  (m89/m91)
  #pragma unroll
  for (int nt = 0; nt < 8; ++nt) {
    int c = (tile0 + nt) * 16 + row16;
    float bv = bias[c];
    int r0 = base_row + kg * 4;
    #pragma unroll
    for (int q = 0; q < 4; ++q)
      out[(size_t)(r0 + q) * NOUT + c] = acc[nt][q] + bv;
  }
}

extern "C" void kernel_launch(void* const* d_in, const int* in_sizes, int n_in,
                              void* d_out, int out_size, void* d_ws, size_t ws_size,
                              hipStream_t stream) {
  const float* x  = (const float*)d_in[0];
  const float* cb = (const float*)d_in[1];   // c_basis (256,256,9)
  const float* ca = (const float*)d_in[2];   // c_act   (256,256)
  float* out = (float*)d_out;

  unsigned short* Bp = (unsigned short*)d_ws;                    // 1 MB
  float* bias = (float*)((char*)d_ws + 8 * NIN * NOUT * 2);      // 1 KB

  cheby_prepack<<<(8 * NIN * NOUT) / 256, 256, 0, stream>>>(cb, ca, Bp);
  cheby_bias<<<NOUT, 64, 0, stream>>>(cb, ca, bias);
  cheby_mfma<<<1024, 256, 0, stream>>>(x, Bp, bias, out);
}

// Round 3
// 74.943 us; speedup vs baseline: 1.1655x; 1.1655x over previous
//
#include <hip/hip_runtime.h>
#include <hip/hip_bf16.h>

// Problem constants
#define BATCH 32768
#define NIN   256
#define NOUT  256
// degrees 1..8 via MFMA; degree 0 (T_0 = 1) folded into per-column bias

typedef __attribute__((ext_vector_type(8))) short bf16x8;
typedef __attribute__((ext_vector_type(4))) float f32x4;
typedef __attribute__((ext_vector_type(2))) float f32x2;

static __device__ __forceinline__ unsigned short bf16_rne(float f) {
  unsigned u = __float_as_uint(f);
  u += 0x7fffu + ((u >> 16) & 1u);
  return (unsigned short)(u >> 16);
}

// fast tanh: t = sign(v) * (1 - z) / (1 + z), z = exp(-2|v|)
static __device__ __forceinline__ float fast_tanh(float v) {
  float a = fabsf(v);
  float z = __expf(-2.0f * a);
  float r = (1.0f - z) * __builtin_amdgcn_rcpf(1.0f + z);
  return copysignf(r, v);
}

static __device__ __forceinline__ void init_state(const f32x4 x0, const f32x4 x1,
                                                  f32x2* cur, f32x2* prev,
                                                  f32x2* t2) {
  #pragma unroll
  for (int p = 0; p < 4; ++p) {
    float va = (p < 2) ? x0[2 * p]     : x1[2 * p - 4];
    float vb = (p < 2) ? x0[2 * p + 1] : x1[2 * p - 3];
    float ta = fast_tanh(va);
    float tb = fast_tanh(vb);
    cur[p]  = (f32x2){ta, tb};        // T_1
    t2[p]   = cur[p] + cur[p];
    prev[p] = (f32x2){1.0f, 1.0f};    // T_0
  }
}

// ---------------------------------------------------------------------------
// Prepack: Bp[((dm*8+ic)*16+tile)*512 + kg*128 + col*8 + j] =
//          bf16( c_basis[n][i][dm+1] * c_act[n][i] )
//   with i = ic*32 + kg*8 + j,  n = tile*16 + col.
// ---------------------------------------------------------------------------
__global__ void cheby_prepack(const float* __restrict__ cb,
                              const float* __restrict__ ca,
                              unsigned short* __restrict__ Bp) {
  int tid = blockIdx.x * 256 + threadIdx.x;
  int j    = tid & 7;
  int col  = (tid >> 3) & 15;
  int kg   = (tid >> 7) & 3;
  int tile = (tid >> 9) & 15;
  int ic   = (tid >> 13) & 7;
  int dm   = tid >> 16;           // d-1, 0..7
  int i = ic * 32 + kg * 8 + j;
  int n = tile * 16 + col;
  float w = cb[n * (NIN * 9) + i * 9 + (dm + 1)] * ca[n * NIN + i];
  Bp[tid] = bf16_rne(w);
}

// bias[n] = sum_i c_basis[n][i][0] * c_act[n][i]   (T_0 == 1 term)
__global__ void cheby_bias(const float* __restrict__ cb,
                           const float* __restrict__ ca,
                           float* __restrict__ bias) {
  int n = blockIdx.x;
  int l = threadIdx.x;            // 64 threads = one wave
  float s = 0.0f;
  #pragma unroll
  for (int k = 0; k < 4; ++k) {
    int i = l + k * 64;
    s += cb[n * (NIN * 9) + i * 9] * ca[n * NIN + i];
  }
  #pragma unroll
  for (int off = 32; off; off >>= 1) s += __shfl_down(s, off);
  if (l == 0) bias[n] = s;
}

// ---------------------------------------------------------------------------
// Fused cheby + GEMM.
// Grid: 512 blocks x 256 threads (4 waves). Block tile: 64 rows x 256 cols.
// Wave tile: 64 rows x 64 cols (4 mt x 4 nt) -> each B load feeds 4 MFMAs,
// each A fragment feeds 4 MFMAs. B prefetched 1 d-step ahead (L2 ~300cy),
// x prefetched 1 ic ahead (HBM ~900cy hidden under the d-loop).
// ---------------------------------------------------------------------------
__global__ __launch_bounds__(256, 2)
void cheby_mfma(const float* __restrict__ x,
                const unsigned short* __restrict__ Bp,
                const float* __restrict__ bias,
                float* __restrict__ out) {
  int w    = threadIdx.x >> 6;    // wave -> column strip
  int lane = threadIdx.x & 63;
  int row16 = lane & 15;          // A row / B col / C-D col
  int kg    = lane >> 4;          // k-group 0..3

  int base_row = blockIdx.x * 64;
  int tile0    = w * 4;           // 4 column tiles of 16 -> 64 cols

  f32x4 acc[4][4];
  #pragma unroll
  for (int a = 0; a < 4; ++a)
    #pragma unroll
    for (int b = 0; b < 4; ++b) acc[a][b] = (f32x4)0.0f;

  // per-lane byte offset inside one 1KB B fragment
  const char* bp_lane = (const char*)Bp + (kg * 256 + row16 * 16);
  const float* xbase = x + (size_t)(base_row + row16) * NIN + kg * 8;

  f32x2 cur[4][4], prev[4][4], t2[4][4];

  // prologue: load + tanh for ic = 0
  #pragma unroll
  for (int mt = 0; mt < 4; ++mt) {
    const float* p = xbase + (size_t)mt * (16 * NIN);
    f32x4 x0 = *(const f32x4*)p;
    f32x4 x1 = *(const f32x4*)(p + 4);
    init_state(x0, x1, cur[mt], prev[mt], t2[mt]);
  }

  for (int ic = 0; ic < 8; ++ic) {
    // prefetch next ic's x early: consumed only after the whole d-loop
    f32x4 xn0[4], xn1[4];
    if (ic < 7) {
      #pragma unroll
      for (int mt = 0; mt < 4; ++mt) {
        const float* p = xbase + (size_t)mt * (16 * NIN) + (ic + 1) * 32;
        xn0[mt] = *(const f32x4*)p;
        xn1[mt] = *(const f32x4*)(p + 4);
      }
    }

    const char* bpi = bp_lane + (size_t)(ic * 16 + tile0) * 1024;
    // d-stride in Bp = 8 ic * 16 tiles * 1024 B = 131072 B
    bf16x8 bcur[4];
    #pragma unroll
    for (int nt = 0; nt < 4; ++nt)
      bcur[nt] = *(const bf16x8*)(bpi + nt * 1024);        // d = 1

    #pragma unroll
    for (int d = 1; d <= 8; ++d) {
      bf16x8 bnxt[4];
      if (d < 8) {
        #pragma unroll
        for (int nt = 0; nt < 4; ++nt)
          bnxt[nt] = *(const bf16x8*)(bpi + (size_t)d * 131072 + nt * 1024);
      }
      #pragma unroll
      for (int mt = 0; mt < 4; ++mt) {
        // A fragment: bf16(T_d), paired converts -> v_cvt_pk_bf16_f32
        union { unsigned u[4]; bf16x8 v; } au;
        #pragma unroll
        for (int p = 0; p < 4; ++p) {
          __hip_bfloat162 h2 = __float22bfloat162_rn(
              make_float2(cur[mt][p][0], cur[mt][p][1]));
          union { __hip_bfloat162 h; unsigned uu; } cv;
          cv.h = h2;
          au.u[p] = cv.uu;
        }
        #pragma unroll
        for (int nt = 0; nt < 4; ++nt)
          acc[mt][nt] = __builtin_amdgcn_mfma_f32_16x16x32_bf16(
              au.v, bcur[nt], acc[mt][nt], 0, 0, 0);
        if (d < 8) {   // T_{d+1} = 2t*T_d - T_{d-1}  (v_pk_fma_f32)
          #pragma unroll
          for (int p = 0; p < 4; ++p) {
            f32x2 nx = __builtin_elementwise_fma(t2[mt][p], cur[mt][p],
                                                 -prev[mt][p]);
            prev[mt][p] = cur[mt][p];
            cur[mt][p]  = nx;
          }
        }
      }
      if (d < 8) {
        #pragma unroll
        for (int nt = 0; nt < 4; ++nt) bcur[nt] = bnxt[nt];
      }
    }

    // tanh for next ic from the prefetched x (loads landed long ago)
    if (ic < 7) {
      #pragma unroll
      for (int mt = 0; mt < 4; ++mt)
        init_state(xn0[mt], xn1[mt], cur[mt], prev[mt], t2[mt]);
    }
  }

  // epilogue: C/D layout col = lane&15, row = (lane>>4)*4 + q  (m89/m91)
  #pragma unroll
  for (int nt = 0; nt < 4; ++nt) {
    int c = (tile0 + nt) * 16 + row16;
    float bv = bias[c];
    #pragma unroll
    for (int mt = 0; mt < 4; ++mt) {
      int r0 = base_row + mt * 16 + kg * 4;
      #pragma unroll
      for (int q = 0; q < 4; ++q)
        out[(size_t)(r0 + q) * NOUT + c] = acc[mt][nt][q] + bv;
    }
  }
}

extern "C" void kernel_launch(void* const* d_in, const int* in_sizes, int n_in,
                              void* d_out, int out_size, void* d_ws, size_t ws_size,
                              hipStream_t stream) {
  const float* x  = (const float*)d_in[0];
  const float* cb = (const float*)d_in[1];   // c_basis (256,256,9)
  const float* ca = (const float*)d_in[2];   // c_act   (256,256)
  float* out = (float*)d_out;

  unsigned short* Bp = (unsigned short*)d_ws;                    // 1 MB
  float* bias = (float*)((char*)d_ws + 8 * NIN * NOUT * 2);      // 1 KB

  cheby_prepack<<<(8 * NIN * NOUT) / 256, 256, 0, stream>>>(cb, ca, Bp);
  cheby_bias<<<NOUT, 64, 0, stream>>>(cb, ca, bias);
  cheby_mfma<<<512, 256, 0, stream>>>(x, Bp, bias, out);
}

// Round 4
// 52.234 us; speedup vs baseline: 1.6722x; 1.4347x over previous
//
#include <hip/hip_runtime.h>
#include <hip/hip_bf16.h>

// Problem constants
#define BATCH 32768
#define NIN   256
#define NOUT  256
// degrees 1..8 via MFMA; degree 0 (T_0 = 1) folded into per-column bias

typedef __attribute__((ext_vector_type(8))) short bf16x8;
typedef __attribute__((ext_vector_type(4))) float f32x4;
typedef __attribute__((ext_vector_type(2))) float f32x2;
typedef __attribute__((ext_vector_type(4))) unsigned int u32x4;

static __device__ __forceinline__ unsigned short bf16_rne(float f) {
  unsigned u = __float_as_uint(f);
  u += 0x7fffu + ((u >> 16) & 1u);
  return (unsigned short)(u >> 16);
}

// fast tanh: t = sign(v) * (1 - z) / (1 + z), z = exp(-2|v|)
static __device__ __forceinline__ float fast_tanh(float v) {
  float a = fabsf(v);
  float z = __expf(-2.0f * a);
  float r = (1.0f - z) * __builtin_amdgcn_rcpf(1.0f + z);
  return copysignf(r, v);
}

static __device__ __forceinline__ unsigned pack_pair(f32x2 v) {
  __hip_bfloat162 h2 = __float22bfloat162_rn(make_float2(v[0], v[1]));
  union { __hip_bfloat162 h; unsigned u; } cv;
  cv.h = h2;
  return cv.u;
}

// ---------------------------------------------------------------------------
// Prepack: Bp[((dm*8+ic)*16+tile)*512 + kg*128 + col*8 + j] =
//          bf16( c_basis[n][i][dm+1] * c_act[n][i] )
//   with i = ic*32 + kg*8 + j,  n = tile*16 + col.
// ---------------------------------------------------------------------------
__global__ void cheby_prepack(const float* __restrict__ cb,
                              const float* __restrict__ ca,
                              unsigned short* __restrict__ Bp) {
  int tid = blockIdx.x * 256 + threadIdx.x;
  int j    = tid & 7;
  int col  = (tid >> 3) & 15;
  int kg   = (tid >> 7) & 3;
  int tile = (tid >> 9) & 15;
  int ic   = (tid >> 13) & 7;
  int dm   = tid >> 16;           // d-1, 0..7
  int i = ic * 32 + kg * 8 + j;
  int n = tile * 16 + col;
  float w = cb[n * (NIN * 9) + i * 9 + (dm + 1)] * ca[n * NIN + i];
  Bp[tid] = bf16_rne(w);
}

// bias[n] = sum_i c_basis[n][i][0] * c_act[n][i]   (T_0 == 1 term)
__global__ void cheby_bias(const float* __restrict__ cb,
                           const float* __restrict__ ca,
                           float* __restrict__ bias) {
  int n = blockIdx.x;
  int l = threadIdx.x;            // 64 threads = one wave
  float s = 0.0f;
  #pragma unroll
  for (int k = 0; k < 4; ++k) {
    int i = l + k * 64;
    s += cb[n * (NIN * 9) + i * 9] * ca[n * NIN + i];
  }
  #pragma unroll
  for (int off = 32; off; off >>= 1) s += __shfl_down(s, off);
  if (l == 0) bias[n] = s;
}

// ---------------------------------------------------------------------------
// Fused cheby + GEMM, LDS-staged A.
// Grid: 512 blocks x 256 threads (4 waves). Block tile: 64 rows x 256 cols.
// Per ic chunk (32 features):
//   compute phase: 256 threads cooperatively tanh+recurrence 64x32 x-elems
//                  (ONCE per block, was 4x duplicated), pack bf16 T_d into
//                  LDS in MFMA fragment layout, double-buffered.
//   MFMA phase:    each wave (64 rows x 64 cols) reads shared A frags from
//                  LDS, B frags from global (L2-resident 1MB), 16 MFMA/d,
//                  next-d A/B prefetched in registers.
// One barrier per ic (double buffer makes the second barrier unnecessary:
// MFMA(ic) precedes barrier(ic+1) in program order for every wave).
// ---------------------------------------------------------------------------
__global__ __launch_bounds__(256, 2)
void cheby_mfma(const float* __restrict__ x,
                const unsigned short* __restrict__ Bp,
                const float* __restrict__ bias,
                float* __restrict__ out) {
  // [buf][d-1][mt][frag: kg*128 + row16*8 + j]  -- 1KB fragments, 64KB total
  __shared__ unsigned short Asm[2][8][4][512];

  int tid  = threadIdx.x;
  int w    = tid >> 6;
  int lane = tid & 63;
  int row16 = lane & 15;          // A row / B col / C-D col
  int kg    = lane >> 4;          // k-group 0..3

  int base_row = blockIdx.x * 64;
  int tile0    = w * 4;           // wave's 4 column tiles (64 cols)

  // writer role: thread -> (row, feature-group-of-8)
  int wrow = tid >> 2;            // 0..63
  int wfg  = tid & 3;             // 0..3
  const float* xw = x + (size_t)(base_row + wrow) * NIN + wfg * 8;
  // LDS write slot (bytes): [buf][d][wrow>>4] + wfg*256 + (wrow&15)*16
  char* wbase = (char*)&Asm[0][0][wrow >> 4][0] + (wfg * 256 + (wrow & 15) * 16);

  // reader roles
  const char* bp_lane = (const char*)Bp + kg * 256 + row16 * 16;
  const char* abase   = (const char*)&Asm[0][0][0][0] + lane * 16;

  f32x4 acc[4][4];
  #pragma unroll
  for (int a = 0; a < 4; ++a)
    #pragma unroll
    for (int b = 0; b < 4; ++b) acc[a][b] = (f32x4)0.0f;

  // prefetch x for ic = 0
  f32x4 xa = *(const f32x4*)xw;
  f32x4 xb = *(const f32x4*)(xw + 4);

  for (int ic = 0; ic < 8; ++ic) {
    int buf = ic & 1;
    // ---- compute phase: tanh + recurrence + pack -> LDS ----
    f32x2 cur[4], prev[4], t2[4];
    #pragma unroll
    for (int p = 0; p < 4; ++p) {
      float va = (p < 2) ? xa[2 * p]     : xb[2 * p - 4];
      float vb = (p < 2) ? xa[2 * p + 1] : xb[2 * p - 3];
      float ta = fast_tanh(va);
      float tb = fast_tanh(vb);
      cur[p]  = (f32x2){ta, tb};        // T_1
      t2[p]   = cur[p] + cur[p];
      prev[p] = (f32x2){1.0f, 1.0f};    // T_0
    }
    char* wp = wbase + buf * 32768;
    #pragma unroll
    for (int d = 1; d <= 8; ++d) {
      u32x4 pk;
      #pragma unroll
      for (int p = 0; p < 4; ++p) pk[p] = pack_pair(cur[p]);
      *(u32x4*)(wp + (d - 1) * 4096) = pk;     // ds_write_b128
      if (d < 8) {   // T_{d+1} = 2t*T_d - T_{d-1}  (v_pk_fma_f32)
        #pragma unroll
        for (int p = 0; p < 4; ++p) {
          f32x2 nx = __builtin_elementwise_fma(t2[p], cur[p], -prev[p]);
          prev[p] = cur[p];
          cur[p]  = nx;
        }
      }
    }
    // prefetch next ic's x (lands under the MFMA phase)
    if (ic < 7) {
      xa = *(const f32x4*)(xw + (ic + 1) * 32);
      xb = *(const f32x4*)(xw + (ic + 1) * 32 + 4);
    }
    __syncthreads();

    // ---- MFMA phase ----
    const char* bpi = bp_lane + (size_t)(ic * 16 + tile0) * 1024;
    const char* ai  = abase + buf * 32768;
    bf16x8 bcur[4], acur[4];
    #pragma unroll
    for (int nt = 0; nt < 4; ++nt)
      bcur[nt] = *(const bf16x8*)(bpi + nt * 1024);
    #pragma unroll
    for (int mt = 0; mt < 4; ++mt)
      acur[mt] = *(const bf16x8*)(ai + mt * 1024);

    #pragma unroll
    for (int d = 1; d <= 8; ++d) {
      bf16x8 bnxt[4], anxt[4];
      if (d < 8) {
        #pragma unroll
        for (int nt = 0; nt < 4; ++nt)
          bnxt[nt] = *(const bf16x8*)(bpi + (size_t)d * 131072 + nt * 1024);
        #pragma unroll
        for (int mt = 0; mt < 4; ++mt)
          anxt[mt] = *(const bf16x8*)(ai + (d * 4 + mt) * 1024);
      }
      #pragma unroll
      for (int mt = 0; mt < 4; ++mt)
        #pragma unroll
        for (int nt = 0; nt < 4; ++nt)
          acc[mt][nt] = __builtin_amdgcn_mfma_f32_16x16x32_bf16(
              acur[mt], bcur[nt], acc[mt][nt], 0, 0, 0);
      if (d < 8) {
        #pragma unroll
        for (int nt = 0; nt < 4; ++nt) bcur[nt] = bnxt[nt];
        #pragma unroll
        for (int mt = 0; mt < 4; ++mt) acur[mt] = anxt[mt];
      }
    }
  }

  // epilogue: C/D layout col = lane&15, row = (lane>>4)*4 + q  (m89/m91)
  #pragma unroll
  for (int nt = 0; nt < 4; ++nt) {
    int c = (tile0 + nt) * 16 + row16;
    float bv = bias[c];
    #pragma unroll
    for (int mt = 0; mt < 4; ++mt) {
      int r0 = base_row + mt * 16 + kg * 4;
      #pragma unroll
      for (int q = 0; q < 4; ++q)
        out[(size_t)(r0 + q) * NOUT + c] = acc[mt][nt][q] + bv;
    }
  }
}

extern "C" void kernel_launch(void* const* d_in, const int* in_sizes, int n_in,
                              void* d_out, int out_size, void* d_ws, size_t ws_size,
                              hipStream_t stream) {
  const float* x  = (const float*)d_in[0];
  const float* cb = (const float*)d_in[1];   // c_basis (256,256,9)
  const float* ca = (const float*)d_in[2];   // c_act   (256,256)
  float* out = (float*)d_out;

  unsigned short* Bp = (unsigned short*)d_ws;                    // 1 MB
  float* bias = (float*)((char*)d_ws + 8 * NIN * NOUT * 2);      // 1 KB

  cheby_prepack<<<(8 * NIN * NOUT) / 256, 256, 0, stream>>>(cb, ca, Bp);
  cheby_bias<<<NOUT, 64, 0, stream>>>(cb, ca, bias);
  cheby_mfma<<<512, 256, 0, stream>>>(x, Bp, bias, out);
}

// Round 5
// 50.250 us; speedup vs baseline: 1.7383x; 1.0395x over previous
//
#include <hip/hip_runtime.h>
#include <hip/hip_bf16.h>

// Problem constants
#define BATCH 32768
#define NIN   256
#define NOUT  256
// degrees 1..8 via MFMA; degree 0 (T_0 = 1) folded into per-column bias

typedef __attribute__((ext_vector_type(8))) short bf16x8;
typedef __attribute__((ext_vector_type(4))) float f32x4;
typedef __attribute__((ext_vector_type(2))) float f32x2;
typedef __attribute__((ext_vector_type(4))) unsigned int u32x4;

static __device__ __forceinline__ unsigned short bf16_rne(float f) {
  unsigned u = __float_as_uint(f);
  u += 0x7fffu + ((u >> 16) & 1u);
  return (unsigned short)(u >> 16);
}

// fast tanh: t = sign(v) * (1 - z) / (1 + z), z = exp(-2|v|)
static __device__ __forceinline__ float fast_tanh(float v) {
  float a = fabsf(v);
  float z = __expf(-2.0f * a);
  float r = (1.0f - z) * __builtin_amdgcn_rcpf(1.0f + z);
  return copysignf(r, v);
}

static __device__ __forceinline__ unsigned pack_pair(f32x2 v) {
  __hip_bfloat162 h2 = __float22bfloat162_rn(make_float2(v[0], v[1]));
  union { __hip_bfloat162 h; unsigned u; } cv;
  cv.h = h2;
  return cv.u;
}

static __device__ __forceinline__ void init_state(const f32x4 x0, const f32x4 x1,
                                                  f32x2* cur, f32x2* prev,
                                                  f32x2* t2) {
  #pragma unroll
  for (int p = 0; p < 4; ++p) {
    float va = (p < 2) ? x0[2 * p]     : x1[2 * p - 4];
    float vb = (p < 2) ? x0[2 * p + 1] : x1[2 * p - 3];
    float ta = fast_tanh(va);
    float tb = fast_tanh(vb);
    cur[p]  = (f32x2){ta, tb};        // T_1
    t2[p]   = cur[p] + cur[p];
    prev[p] = (f32x2){1.0f, 1.0f};    // T_0
  }
}

// ---------------------------------------------------------------------------
// Prepack: Bp[((dm*8+ic)*16+tile)*512 + kg*128 + col*8 + j] =
//          bf16( c_basis[n][i][dm+1] * c_act[n][i] )
//   with i = ic*32 + kg*8 + j,  n = tile*16 + col.
// ---------------------------------------------------------------------------
__global__ void cheby_prepack(const float* __restrict__ cb,
                              const float* __restrict__ ca,
                              unsigned short* __restrict__ Bp) {
  int tid = blockIdx.x * 256 + threadIdx.x;
  int j    = tid & 7;
  int col  = (tid >> 3) & 15;
  int kg   = (tid >> 7) & 3;
  int tile = (tid >> 9) & 15;
  int ic   = (tid >> 13) & 7;
  int dm   = tid >> 16;           // d-1, 0..7
  int i = ic * 32 + kg * 8 + j;
  int n = tile * 16 + col;
  float w = cb[n * (NIN * 9) + i * 9 + (dm + 1)] * ca[n * NIN + i];
  Bp[tid] = bf16_rne(w);
}

// bias[n] = sum_i c_basis[n][i][0] * c_act[n][i]   (T_0 == 1 term)
__global__ void cheby_bias(const float* __restrict__ cb,
                           const float* __restrict__ ca,
                           float* __restrict__ bias) {
  int n = blockIdx.x;
  int l = threadIdx.x;            // 64 threads = one wave
  float s = 0.0f;
  #pragma unroll
  for (int k = 0; k < 4; ++k) {
    int i = l + k * 64;
    s += cb[n * (NIN * 9) + i * 9] * ca[n * NIN + i];
  }
  #pragma unroll
  for (int off = 32; off; off >>= 1) s += __shfl_down(s, off);
  if (l == 0) bias[n] = s;
}

// ---------------------------------------------------------------------------
// Fused cheby + GEMM, software-pipelined LDS-staged A.
// Grid: 512 blocks x 256 threads (4 waves). Block tile: 64 rows x 256 cols.
// Iteration ic: MFMA on buf (written last iter) INTERLEAVED with
// tanh+recurrence+pack of ic+1 into buf^1, one barrier at the end.
// VALU+ds_write issue in the MFMA shadow (separate pipes).
// Writer: wave w owns plane mt=w, lane writes at lane*16 -> per-wave
// contiguous 1024B ds_write_b128, zero bank conflicts.
// ---------------------------------------------------------------------------
__global__ __launch_bounds__(256, 2)
void cheby_mfma(const float* __restrict__ x,
                const unsigned short* __restrict__ Bp,
                const float* __restrict__ bias,
                float* __restrict__ out) {
  // [buf][d-1][mt][frag: kg*256B + row16*16B]  -- 1KB fragments, 64KB total
  __shared__ unsigned short Asm[2][8][4][512];

  int tid  = threadIdx.x;
  int w    = tid >> 6;
  int lane = tid & 63;
  int row16 = lane & 15;          // A row / B col / C-D col
  int kg    = lane >> 4;          // k-group 0..3

  int base_row = blockIdx.x * 64;
  int tile0    = w * 4;           // wave's 4 column tiles (64 cols)

  // writer role: wave w covers rows w*16..w*16+15 (plane mt=w), lane ->
  // (row16 = lane&15, fg = lane>>4); LDS slot = plane base + lane*16.
  const float* xw = x + (size_t)(base_row + w * 16 + row16) * NIN + kg * 8;
  char* wbase = (char*)Asm + (w * 1024 + lane * 16);
  // reader
  const char* abase   = (const char*)Asm + lane * 16;
  const char* bp_lane = (const char*)Bp + kg * 256 + row16 * 16;

  f32x4 acc[4][4];
  #pragma unroll
  for (int a = 0; a < 4; ++a)
    #pragma unroll
    for (int b = 0; b < 4; ++b) acc[a][b] = (f32x4)0.0f;

  // ---- prologue: compute + write buf0 for ic=0 ----
  f32x4 xa = *(const f32x4*)xw;
  f32x4 xb = *(const f32x4*)(xw + 4);
  {
    f32x2 cur[4], prev[4], t2[4];
    init_state(xa, xb, cur, prev, t2);
    #pragma unroll
    for (int d = 1; d <= 8; ++d) {
      u32x4 pk;
      #pragma unroll
      for (int p = 0; p < 4; ++p) pk[p] = pack_pair(cur[p]);
      *(u32x4*)(wbase + (d - 1) * 4096) = pk;
      if (d < 8) {
        #pragma unroll
        for (int p = 0; p < 4; ++p) {
          f32x2 nx = __builtin_elementwise_fma(t2[p], cur[p], -prev[p]);
          prev[p] = cur[p];
          cur[p]  = nx;
        }
      }
    }
  }
  // x for ic=1 (consumed at top of iteration 0)
  xa = *(const f32x4*)(xw + 32);
  xb = *(const f32x4*)(xw + 36);
  __syncthreads();

  // ---- main loop: MFMA(ic) || compute+write(ic+1) ----
  for (int ic = 0; ic < 7; ++ic) {
    int buf = ic & 1;
    f32x2 cur[4], prev[4], t2[4];
    init_state(xa, xb, cur, prev, t2);            // state for ic+1
    if (ic < 6) {                                 // prefetch x for ic+2
      xa = *(const f32x4*)(xw + (ic + 2) * 32);
      xb = *(const f32x4*)(xw + (ic + 2) * 32 + 4);
    }
    const char* ai  = abase + buf * 32768;
    char*       wp  = wbase + (buf ^ 1) * 32768;
    const char* bpi = bp_lane + (size_t)(ic * 16 + tile0) * 1024;

    #pragma unroll
    for (int d = 1; d <= 8; ++d) {
      bf16x8 af[4], bfr[4];
      #pragma unroll
      for (int mt = 0; mt < 4; ++mt)
        af[mt] = *(const bf16x8*)(ai + (d - 1) * 4096 + mt * 1024);
      #pragma unroll
      for (int nt = 0; nt < 4; ++nt)
        bfr[nt] = *(const bf16x8*)(bpi + (size_t)(d - 1) * 131072 + nt * 1024);
      // pack + write degree d of NEXT ic (issues under the MFMAs below)
      u32x4 pk;
      #pragma unroll
      for (int p = 0; p < 4; ++p) pk[p] = pack_pair(cur[p]);
      *(u32x4*)(wp + (d - 1) * 4096) = pk;
      if (d < 8) {   // T_{d+1} = 2t*T_d - T_{d-1}  (v_pk_fma_f32)
        #pragma unroll
        for (int p = 0; p < 4; ++p) {
          f32x2 nx = __builtin_elementwise_fma(t2[p], cur[p], -prev[p]);
          prev[p] = cur[p];
          cur[p]  = nx;
        }
      }
      #pragma unroll
      for (int mt = 0; mt < 4; ++mt)
        #pragma unroll
        for (int nt = 0; nt < 4; ++nt)
          acc[mt][nt] = __builtin_amdgcn_mfma_f32_16x16x32_bf16(
              af[mt], bfr[nt], acc[mt][nt], 0, 0, 0);
    }
    __syncthreads();
  }

  // ---- final iteration ic=7: MFMA only (buf=1) ----
  {
    const char* ai  = abase + 32768;
    const char* bpi = bp_lane + (size_t)(7 * 16 + tile0) * 1024;
    #pragma unroll
    for (int d = 1; d <= 8; ++d) {
      bf16x8 af[4], bfr[4];
      #pragma unroll
      for (int mt = 0; mt < 4; ++mt)
        af[mt] = *(const bf16x8*)(ai + (d - 1) * 4096 + mt * 1024);
      #pragma unroll
      for (int nt = 0; nt < 4; ++nt)
        bfr[nt] = *(const bf16x8*)(bpi + (size_t)(d - 1) * 131072 + nt * 1024);
      #pragma unroll
      for (int mt = 0; mt < 4; ++mt)
        #pragma unroll
        for (int nt = 0; nt < 4; ++nt)
          acc[mt][nt] = __builtin_amdgcn_mfma_f32_16x16x32_bf16(
              af[mt], bfr[nt], acc[mt][nt], 0, 0, 0);
    }
  }

  // epilogue: C/D layout col = lane&15, row = (lane>>4)*4 + q  (m89/m91)
  #pragma unroll
  for (int nt = 0; nt < 4; ++nt) {
    int c = (tile0 + nt) * 16 + row16;
    float bv = bias[c];
    #pragma unroll
    for (int mt = 0; mt < 4; ++mt) {
      int r0 = base_row + mt * 16 + kg * 4;
      #pragma unroll
      for (int q = 0; q < 4; ++q)
        out[(size_t)(r0 + q) * NOUT + c] = acc[mt][nt][q] + bv;
    }
  }
}

extern "C" void kernel_launch(void* const* d_in, const int* in_sizes, int n_in,
                              void* d_out, int out_size, void* d_ws, size_t ws_size,
                              hipStream_t stream) {
  const float* x  = (const float*)d_in[0];
  const float* cb = (const float*)d_in[1];   // c_basis (256,256,9)
  const float* ca = (const float*)d_in[2];   // c_act   (256,256)
  float* out = (float*)d_out;

  unsigned short* Bp = (unsigned short*)d_ws;                    // 1 MB
  float* bias = (float*)((char*)d_ws + 8 * NIN * NOUT * 2);      // 1 KB

  cheby_prepack<<<(8 * NIN * NOUT) / 256, 256, 0, stream>>>(cb, ca, Bp);
  cheby_bias<<<NOUT, 64, 0, stream>>>(cb, ca, bias);
  cheby_mfma<<<512, 256, 0, stream>>>(x, Bp, bias, out);
}